// Round 9
// baseline (129.604 us; speedup 1.0000x reference)
//
#include <hip/hip_runtime.h>
#include <math.h>

// Problem constants: B=4, N=256, C=512, H=8, Dh=64
#define BB 4
#define NN 256
#define CC 512
#define HH 8
#define DH 64

typedef __attribute__((ext_vector_type(8))) short bf16x8;
typedef __attribute__((ext_vector_type(4))) float f32x4;
typedef __attribute__((ext_vector_type(2))) float f32x2;

__device__ inline unsigned short f2bf(float f) {
  unsigned u = __float_as_uint(f);
  u += 0x7FFFu + ((u >> 16) & 1u);  // round-to-nearest-even
  return (unsigned short)(u >> 16);
}
__device__ inline float bf2f(unsigned short s) {
  return __uint_as_float((unsigned)s << 16);
}

// Forced packed-fp32 ops (gfx90a+ VOP3P). "v" on f32x2 -> aligned VGPR pair.
// No volatile / no memory clobber: scheduler may interleave with v_sin.
#define PK_ADD(dst, a, b) \
  asm("v_pk_add_f32 %0, %1, %2" : "=v"(dst) : "v"(a), "v"(b))
#define PK_MUL(dst, a, b) \
  asm("v_pk_mul_f32 %0, %1, %2" : "=v"(dst) : "v"(a), "v"(b))

// ---------------------------------------------------------------------------
// Fused fp32 -> (hi, lo) bf16 split for all three inputs in ONE launch.
// Segments (blocks): x = 512, w_qkv = 768, w_proj = 256  -> grid 1536.
// ---------------------------------------------------------------------------
__global__ __launch_bounds__(256) void cvt_hilo3(
    const float* __restrict__ in0, unsigned short* __restrict__ h0,
    unsigned short* __restrict__ l0, const float* __restrict__ in1,
    unsigned short* __restrict__ h1, unsigned short* __restrict__ l1,
    const float* __restrict__ in2, unsigned short* __restrict__ h2,
    unsigned short* __restrict__ l2) {
  int b = blockIdx.x;
  const float* in;
  unsigned short *h, *l;
  if (b < 512) {
    in = in0; h = h0; l = l0;
  } else if (b < 1280) {
    in = in1; h = h1; l = l1; b -= 512;
  } else {
    in = in2; h = h2; l = l2; b -= 1280;
  }
  int i = (b * 256 + threadIdx.x) * 4;
  float4 f = *(const float4*)(in + i);
  float fa[4] = {f.x, f.y, f.z, f.w};
  ushort4 hv, lv;
  unsigned short* hp = (unsigned short*)&hv;
  unsigned short* lp = (unsigned short*)&lv;
#pragma unroll
  for (int j = 0; j < 4; j++) {
    unsigned short hb = f2bf(fa[j]);
    hp[j] = hb;
    lp[j] = f2bf(fa[j] - bf2f(hb));
  }
  *(ushort4*)(h + i) = hv;
  *(ushort4*)(l + i) = lv;
}

// ---------------------------------------------------------------------------
// MFMA GEMM, bf16 hi/lo split (3 products): C = A * B^T (+bias).
// r3-proven structure: LDS double-buffer, ONE barrier per K-step.
// 256 thr = 4 waves; tile 64x64; wave -> 32x32 (2x2 mfma 16x16x32). BK=64.
// LDS rows padded to 72 shorts (144B): b128 frags conflict-free. 72KB LDS.
// ---------------------------------------------------------------------------
template <bool BIAS>
__global__ __launch_bounds__(256, 2) void gemm_mfma(
    const unsigned short* __restrict__ Ah, const unsigned short* __restrict__ Al,
    const unsigned short* __restrict__ Bh, const unsigned short* __restrict__ Bl,
    const float* __restrict__ bias, float* __restrict__ C, int M, int N,
    int K) {
  __shared__ unsigned short sAh[2][64][72], sAl[2][64][72];
  __shared__ unsigned short sBh[2][64][72], sBl[2][64][72];
  const int t = threadIdx.x;
  const int lane = t & 63;
  const int w = t >> 6;
  const int bm = blockIdx.y * 64;
  const int bn = blockIdx.x * 64;
  const int wr = (w >> 1) * 32;  // wave row offset in tile
  const int wc = (w & 1) * 32;   // wave col offset
  const int quad = lane >> 4;
  const int l16 = lane & 15;

  // staging: 512 slots of 8 shorts per array
  const int r0 = t >> 3;       // 0..31
  const int r1 = r0 + 32;      // 32..63
  const int c8 = (t & 7) * 8;  // 0..56

  const size_t a0 = (size_t)(bm + r0) * K + c8;
  const size_t a1 = (size_t)(bm + r1) * K + c8;
  const size_t b0 = (size_t)(bn + r0) * K + c8;
  const size_t b1 = (size_t)(bn + r1) * K + c8;

  f32x4 acc[2][2];
#pragma unroll
  for (int i = 0; i < 2; i++)
#pragma unroll
    for (int j = 0; j < 2; j++) {
      acc[i][j][0] = 0.f;
      acc[i][j][1] = 0.f;
      acc[i][j][2] = 0.f;
      acc[i][j][3] = 0.f;
    }

  uint4 pa0, pa1, pa2, pa3, pb0, pb1, pb2, pb3;
#define GLOADS(K0)                       \
  pa0 = *(const uint4*)(Ah + a0 + (K0)); \
  pa1 = *(const uint4*)(Ah + a1 + (K0)); \
  pa2 = *(const uint4*)(Al + a0 + (K0)); \
  pa3 = *(const uint4*)(Al + a1 + (K0)); \
  pb0 = *(const uint4*)(Bh + b0 + (K0)); \
  pb1 = *(const uint4*)(Bh + b1 + (K0)); \
  pb2 = *(const uint4*)(Bl + b0 + (K0)); \
  pb3 = *(const uint4*)(Bl + b1 + (K0));

#define STORE(P)                  \
  *(uint4*)&sAh[P][r0][c8] = pa0; \
  *(uint4*)&sAh[P][r1][c8] = pa1; \
  *(uint4*)&sAl[P][r0][c8] = pa2; \
  *(uint4*)&sAl[P][r1][c8] = pa3; \
  *(uint4*)&sBh[P][r0][c8] = pb0; \
  *(uint4*)&sBh[P][r1][c8] = pb1; \
  *(uint4*)&sBl[P][r0][c8] = pb2; \
  *(uint4*)&sBl[P][r1][c8] = pb3;

  GLOADS(0)
  STORE(0)
  __syncthreads();
  GLOADS(64)

  int p = 0;
  for (int k0 = 0; k0 < K; k0 += 64) {
#pragma unroll
    for (int kk = 0; kk < 2; kk++) {
      const int kc = kk * 32 + quad * 8;
      bf16x8 ah[2], al[2], bh[2], bl[2];
#pragma unroll
      for (int i = 0; i < 2; i++) {
        ah[i] = *(const bf16x8*)&sAh[p][wr + i * 16 + l16][kc];
        al[i] = *(const bf16x8*)&sAl[p][wr + i * 16 + l16][kc];
        bh[i] = *(const bf16x8*)&sBh[p][wc + i * 16 + l16][kc];
        bl[i] = *(const bf16x8*)&sBl[p][wc + i * 16 + l16][kc];
      }
#pragma unroll
      for (int i = 0; i < 2; i++)
#pragma unroll
        for (int j = 0; j < 2; j++) {
          acc[i][j] = __builtin_amdgcn_mfma_f32_16x16x32_bf16(
              ah[i], bh[j], acc[i][j], 0, 0, 0);
          acc[i][j] = __builtin_amdgcn_mfma_f32_16x16x32_bf16(
              ah[i], bl[j], acc[i][j], 0, 0, 0);
          acc[i][j] = __builtin_amdgcn_mfma_f32_16x16x32_bf16(
              al[i], bh[j], acc[i][j], 0, 0, 0);
        }
    }
    if (k0 + 64 < K) {
      STORE(p ^ 1)
      if (k0 + 128 < K) {
        GLOADS(k0 + 128)
      }
    }
    __syncthreads();
    p ^= 1;
  }
#undef GLOADS
#undef STORE

  // epilogue: C/D layout col=lane&15, row=quad*4+reg (verified m89/m91)
#pragma unroll
  for (int i = 0; i < 2; i++)
#pragma unroll
    for (int j = 0; j < 2; j++) {
      int n = bn + wc + j * 16 + l16;
      float bv = BIAS ? bias[n] : 0.f;
#pragma unroll
      for (int r = 0; r < 4; r++) {
        int m = bm + wr + i * 16 + quad * 4 + r;
        C[(size_t)m * N + n] = acc[i][j][r] + bv;
      }
    }
}

// ---------------------------------------------------------------------------
// Fused Fourier attention v10 = r8 structure + FORCED v_pk packed math.
// r8 forensics: VALUBusy 55.8% of 41us = 3.4K cyc/wave-tile issue — matches
// the SCALAR-codegen op count exactly (640 scalar + 128 v_sin@8cyc + ovh);
// packed would be ~2.4K. hipcc unpacks our f32x2 because the scalar sin
// uses of g.x/g.y contaminate ISel. Fix: inline-asm v_pk_add/mul_f32 for
// the d/g/dn chains; nm accumulation stays scalar (sin outputs never need
// re-pairing); K staged NEGATED so q-k becomes pk_add (exact, bit-identical
// ordering (q + (-k)) + eps — collision-safe per r2 post-mortem).
// Structure unchanged: 256 thr / 4 waves, 8 queries, one 64-key tile/block,
// 4096 blocks, 4-way partial num/den, V from global (L2, XCD-local id%8=h).
// NO launch_bounds min-arg (r5/r6 spill lesson).
// ---------------------------------------------------------------------------
__global__ __launch_bounds__(256) void fourier_attn(
    const float* __restrict__ qkv, const float* __restrict__ paramR,
    float* __restrict__ num0, float* __restrict__ num1,
    float* __restrict__ num2, float* __restrict__ num3,
    float* __restrict__ den0, float* __restrict__ den1,
    float* __restrict__ den2, float* __restrict__ den3) {
  __shared__ float Kt[64][68];            // NEGATED K tile, row-major, padded
  __shared__ float Qs[8][64];             // 8 staged queries
  __shared__ unsigned short Pah[16][72];  // a4 hi (rows 8-15 zeroed)
  __shared__ unsigned short Pal[16][72];  // a4 lo

  const int t = threadIdx.x;
  const int lane = t & 63;
  const int wv = t >> 6;  // 0..3
  const int quad = lane >> 4;
  const int l16 = lane & 15;
  const int h = blockIdx.x & 7;
  const int b = blockIdx.x >> 3;
  const int qg = blockIdx.y >> 2;  // 0..31: 8-query group
  const int kc4 = blockIdx.y & 3;  // 0..3: 64-key tile
  const float R = paramR[0];
  const float cR = R * 0.15915494309189535f;  // R / (2*pi)

  const float* base = qkv + (size_t)b * NN * (3 * CC) + h * DH;
  const int jt64 = kc4 * 64;

  // ---- stage: NEGATED K tile (4 slots/thread), 8 queries, zero P pad rows
  float4 pk[4];
#pragma unroll
  for (int s = 0; s < 4; s++) {
    int u = t + 256 * s;
    int r = u >> 4;
    int c4 = (u & 15) << 2;
    pk[s] = *(const float4*)(base + (size_t)(jt64 + r) * (3 * CC) + CC + c4);
  }
  if (t < 128) {
    int r = t >> 4;
    int c4 = (t & 15) << 2;
    *(float4*)&Qs[r][c4] =
        *(const float4*)(base + (size_t)(qg * 8 + r) * (3 * CC) + c4);
  }
  if (t < 288) {  // zero uints 288..575 = ushort rows 8..15
    ((unsigned*)Pah)[288 + t] = 0u;
    ((unsigned*)Pal)[288 + t] = 0u;
  }
#pragma unroll
  for (int s = 0; s < 4; s++) {
    int u = t + 256 * s;
    int r = u >> 4;
    int c4 = (u & 15) << 2;
    float4 nk = make_float4(-pk[s].x, -pk[s].y, -pk[s].z, -pk[s].w);
    *(float4*)&Kt[r][c4] = nk;
  }
  __syncthreads();  // B1: Kt, Qs, P-pad ready

  const int qi0 = wv * 2, qi1 = wv * 2 + 1;  // this wave's 2 queries (0..7)
  const int nc = wv;                         // this wave's dim chunk
  const int vcol = nc * 16 + l16;

  // ---- score phase: lane = key; forced-pk d/g/dn chains, scalar nm chains
  const f32x2 eps2 = {1e-30f, 1e-30f};
  const f32x2 cR2 = {cR, cR};
  float nm0[4] = {1.f, 1.f, 1.f, 1.f};  // query 0: 4 scalar chains
  float nm1[4] = {1.f, 1.f, 1.f, 1.f};  // query 1
  f32x2 dnA0 = {1.f, 1.f}, dnB0 = {1.f, 1.f};
  f32x2 dnA1 = {1.f, 1.f}, dnB1 = {1.f, 1.f};
#pragma unroll
  for (int d4 = 0; d4 < 16; d4++) {
    f32x2 knA = *(const f32x2*)&Kt[lane][4 * d4];      // negated k, dims 0,1
    f32x2 knB = *(const f32x2*)&Kt[lane][4 * d4 + 2];  // dims 2,3
    f32x2 qA0 = *(const f32x2*)&Qs[qi0][4 * d4];
    f32x2 qB0 = *(const f32x2*)&Qs[qi0][4 * d4 + 2];
    f32x2 qA1 = *(const f32x2*)&Qs[qi1][4 * d4];
    f32x2 qB1 = *(const f32x2*)&Qs[qi1][4 * d4 + 2];
    f32x2 dA0, dB0, dA1, dB1, gA0, gB0, gA1, gB1;
    // d = (q + (-k)) + eps  — same fp ops/order as (q-k)+eps
    PK_ADD(dA0, qA0, knA);
    PK_ADD(dB0, qB0, knB);
    PK_ADD(dA1, qA1, knA);
    PK_ADD(dB1, qB1, knB);
    PK_ADD(dA0, dA0, eps2);
    PK_ADD(dB0, dB0, eps2);
    PK_ADD(dA1, dA1, eps2);
    PK_ADD(dB1, dB1, eps2);
    PK_MUL(gA0, cR2, dA0);
    PK_MUL(gB0, cR2, dB0);
    PK_MUL(gA1, cR2, dA1);
    PK_MUL(gB1, cR2, dB1);
    nm0[0] *= __builtin_amdgcn_sinf(gA0[0]);
    nm0[1] *= __builtin_amdgcn_sinf(gA0[1]);
    nm0[2] *= __builtin_amdgcn_sinf(gB0[0]);
    nm0[3] *= __builtin_amdgcn_sinf(gB0[1]);
    nm1[0] *= __builtin_amdgcn_sinf(gA1[0]);
    nm1[1] *= __builtin_amdgcn_sinf(gA1[1]);
    nm1[2] *= __builtin_amdgcn_sinf(gB1[0]);
    nm1[3] *= __builtin_amdgcn_sinf(gB1[1]);
    PK_MUL(dnA0, dnA0, dA0);
    PK_MUL(dnB0, dnB0, dB0);
    PK_MUL(dnA1, dnA1, dA1);
    PK_MUL(dnB1, dnB1, dB1);
  }

  // ---- V loads for both key-halves (L2-hot; hidden under finalize + B2)
  float vfa[8], vfb[8];
#pragma unroll
  for (int j = 0; j < 8; j++) {
    vfa[j] = base[(size_t)(jt64 + quad * 8 + j) * (3 * CC) + 2 * CC + vcol];
    vfb[j] =
        base[(size_t)(jt64 + 32 + quad * 8 + j) * (3 * CC) + 2 * CC + vcol];
  }

  // ---- finalize scores -> a4, per-query partial denominators
  float Sp[2];
  {
    float n0 = (nm0[0] * nm0[1]) * (nm0[2] * nm0[3]);
    float n1 = (nm1[0] * nm1[1]) * (nm1[2] * nm1[3]);
    f32x2 d0p, d1p;
    PK_MUL(d0p, dnA0, dnB0);
    PK_MUL(d1p, dnA1, dnB1);
    float d0 = d0p[0] * d0p[1];
    float d1 = d1p[0] * d1p[1];
    float sc0 = n0 / d0;
    float sc1 = n1 / d1;
    float t0 = sc0 * sc0, t1 = sc1 * sc1;
    float a40 = t0 * t0, a41 = t1 * t1;
    Sp[0] = a40;
    Sp[1] = a41;
    unsigned short h0 = f2bf(a40), h1 = f2bf(a41);
    Pah[qi0][lane] = h0;
    Pal[qi0][lane] = f2bf(a40 - bf2f(h0));
    Pah[qi1][lane] = h1;
    Pal[qi1][lane] = f2bf(a41 - bf2f(h1));
  }
  __syncthreads();  // B2: P tile complete

  // ---- AV phase: both key-halves, 6 MFMA into private oacc
  f32x4 oacc;
  oacc[0] = 0.f; oacc[1] = 0.f; oacc[2] = 0.f; oacc[3] = 0.f;
  {
    bf16x8 pah0 = *(const bf16x8*)&Pah[l16][quad * 8];
    bf16x8 pal0 = *(const bf16x8*)&Pal[l16][quad * 8];
    bf16x8 pah1 = *(const bf16x8*)&Pah[l16][32 + quad * 8];
    bf16x8 pal1 = *(const bf16x8*)&Pal[l16][32 + quad * 8];
    bf16x8 vh0, vl0, vh1, vl1;
#pragma unroll
    for (int j = 0; j < 8; j++) {
      unsigned short hb;
      hb = f2bf(vfa[j]);
      vh0[j] = (short)hb;
      vl0[j] = (short)f2bf(vfa[j] - bf2f(hb));
      hb = f2bf(vfb[j]);
      vh1[j] = (short)hb;
      vl1[j] = (short)f2bf(vfb[j] - bf2f(hb));
    }
    __builtin_amdgcn_s_setprio(1);
    oacc = __builtin_amdgcn_mfma_f32_16x16x32_bf16(pah0, vh0, oacc, 0, 0, 0);
    oacc = __builtin_amdgcn_mfma_f32_16x16x32_bf16(pah0, vl0, oacc, 0, 0, 0);
    oacc = __builtin_amdgcn_mfma_f32_16x16x32_bf16(pal0, vh0, oacc, 0, 0, 0);
    oacc = __builtin_amdgcn_mfma_f32_16x16x32_bf16(pah1, vh1, oacc, 0, 0, 0);
    oacc = __builtin_amdgcn_mfma_f32_16x16x32_bf16(pah1, vl1, oacc, 0, 0, 0);
    oacc = __builtin_amdgcn_mfma_f32_16x16x32_bf16(pal1, vh1, oacc, 0, 0, 0);
    __builtin_amdgcn_s_setprio(0);
  }

  // ---- write partial den (per query) + partial num (fp32)
  float* nump = (kc4 == 0) ? num0 : (kc4 == 1) ? num1 : (kc4 == 2) ? num2
                                                                   : num3;
  float* denp = (kc4 == 0) ? den0 : (kc4 == 1) ? den1 : (kc4 == 2) ? den2
                                                                   : den3;
#pragma unroll
  for (int q = 0; q < 2; q++) {
    float s = Sp[q];
#pragma unroll
    for (int off = 32; off > 0; off >>= 1) s += __shfl_xor(s, off, 64);
    if (lane == 0) {
      int m = b * NN + qg * 8 + qi0 + q;
      denp[(size_t)m * HH + h] = s;
    }
  }
#pragma unroll
  for (int r = 0; r < 4; r++) {
    int q = quad * 4 + r;  // 0..15; valid queries are 0..7
    if (q < 8) {
      int m = b * NN + qg * 8 + q;
      nump[(size_t)m * CC + h * DH + nc * 16 + l16] = oacc[r];
    }
  }
}

// ---------------------------------------------------------------------------
// combine_norm: aoh/aol = hi/lo bf16 of (Σ num_i)/(Σ den_i + 1e-6).
// 524288 elems, 4/thread -> 512 blocks x 256.
// ---------------------------------------------------------------------------
__global__ __launch_bounds__(256) void combine_norm(
    const float* __restrict__ num0, const float* __restrict__ num1,
    const float* __restrict__ num2, const float* __restrict__ num3,
    const float* __restrict__ den0, const float* __restrict__ den1,
    const float* __restrict__ den2, const float* __restrict__ den3,
    unsigned short* __restrict__ aoh, unsigned short* __restrict__ aol) {
  int e = (blockIdx.x * 256 + threadIdx.x) * 4;
  int m = e >> 9;         // row (b*N+n)
  int hd = (e >> 6) & 7;  // head
  size_t di = (size_t)m * HH + hd;
  float den = ((den0[di] + den1[di]) + (den2[di] + den3[di])) + 1e-6f;
  float4 n0 = *(const float4*)(num0 + e);
  float4 n1 = *(const float4*)(num1 + e);
  float4 n2 = *(const float4*)(num2 + e);
  float4 n3 = *(const float4*)(num3 + e);
  float o[4] = {((n0.x + n1.x) + (n2.x + n3.x)) / den,
                ((n0.y + n1.y) + (n2.y + n3.y)) / den,
                ((n0.z + n1.z) + (n2.z + n3.z)) / den,
                ((n0.w + n1.w) + (n2.w + n3.w)) / den};
  ushort4 hv, lv;
  unsigned short* hp = (unsigned short*)&hv;
  unsigned short* lp = (unsigned short*)&lv;
#pragma unroll
  for (int j = 0; j < 4; j++) {
    unsigned short hb = f2bf(o[j]);
    hp[j] = hb;
    lp[j] = f2bf(o[j] - bf2f(hb));
  }
  *(ushort4*)(aoh + e) = hv;
  *(ushort4*)(aol + e) = lv;
}

// ---------------------------------------------------------------------------
extern "C" void kernel_launch(void* const* d_in, const int* in_sizes, int n_in,
                              void* d_out, int out_size, void* d_ws,
                              size_t ws_size, hipStream_t stream) {
  const float* x = (const float*)d_in[0];       // (B,N,C)
  const float* w_qkv = (const float*)d_in[1];   // (3C, C)
  const float* w_proj = (const float*)d_in[2];  // (C, C)
  const float* b_proj = (const float*)d_in[3];  // (C,)
  const float* paramR = (const float*)d_in[4];  // (1,)
  float* outp = (float*)d_out;                  // (B,N,C)

  const int nX = BB * NN * CC;  // 524288
  const int nWq = 3 * CC * CC;  // 786432
  const int nWp = CC * CC;      // 262144

  // ws layout: bf16 buffers first (8.4 MB, 16B-aligned), then fp32
  unsigned short* xh = (unsigned short*)d_ws;
  unsigned short* xl = xh + nX;
  unsigned short* wqh = xl + nX;
  unsigned short* wql = wqh + nWq;
  unsigned short* wph = wql + nWq;
  unsigned short* wpl = wph + nWp;
  unsigned short* aoh = wpl + nWp;
  unsigned short* aol = aoh + nX;
  float* qkv_ws = (float*)(aol + nX);  // 1024*1536 fp32
  float* num0 = qkv_ws + 1024 * 1536;  // 4x 1024*512
  float* num1 = num0 + nX;
  float* num2 = num1 + nX;
  float* num3 = num2 + nX;
  float* den0 = num3 + nX;  // 4x 1024*8
  float* den1 = den0 + 1024 * HH;
  float* den2 = den1 + 1024 * HH;
  float* den3 = den2 + 1024 * HH;

  // 1) hi/lo conversions (single fused launch)
  cvt_hilo3<<<1536, 256, 0, stream>>>(x, xh, xl, w_qkv, wqh, wql, w_proj, wph,
                                      wpl);

  // 2) qkv = x @ w_qkv^T : M=1024, N=1536, K=512 (384 blocks)
  gemm_mfma<false><<<dim3(3 * CC / 64, BB * NN / 64), 256, 0, stream>>>(
      xh, xl, wqh, wql, nullptr, qkv_ws, BB * NN, 3 * CC, CC);

  // 3) fused fourier attention, key-split 4-way, 256-thread blocks
  //    grid (x = b*8+h [32], y = qg*4+kc4 [128]) = 4096 blocks
  fourier_attn<<<dim3(HH * BB, (NN / 8) * 4), 256, 0, stream>>>(
      qkv_ws, paramR, num0, num1, num2, num3, den0, den1, den2, den3);

  // 4) combine + normalize -> hi/lo bf16 attention output
  combine_norm<<<nX / 1024, 256, 0, stream>>>(num0, num1, num2, num3, den0,
                                              den1, den2, den3, aoh, aol);

  // 5) out = attn @ w_proj^T + b_proj : M=1024, N=512, K=512 (128 blocks)
  gemm_mfma<true><<<dim3(CC / 64, BB * NN / 64), 256, 0, stream>>>(
      aoh, aol, wph, wpl, b_proj, outp, BB * NN, CC, CC);
}